// Round 1
// baseline (137.514 us; speedup 1.0000x reference)
//
#include <hip/hip_runtime.h>

#define C_DIM 256
#define S_DIM 512
#define P_DIM 128
#define K_DIM 512
#define INV_BW 20.0f
#define EPS_LOSS 1e-5f

// workspace layout (float offsets)
#define OFF_SS2  0                         // [2][512] sumsq of t2 columns
#define OFF_SS1  1024                      // [2][512] sumsq of t1 columns
#define OFF_E    2048                      // [2][512][512] exp(G/bw)
#define OFF_ET   (OFF_E  + 524288)         // [2][512][512] transpose
#define OFF_CNT  (OFF_ET + 524288)         // [128][512] histogram (float)
#define OFF_D1   (OFF_CNT + 65536)         // [128][2][512]
#define OFF_D2   (OFF_D1 + 131072)         // [128][2][512]
#define OFF_PART (OFF_D2 + 131072)         // [128] per-p partial loss sums

// K1: per-(b,s) channel sum-of-squares for both tensors. 16 blocks x 512 thr,
// each block does 32 channels, atomicAdd into zeroed accumulators.
__global__ __launch_bounds__(512) void sumsq_kernel(
    const float* __restrict__ t2, const float* __restrict__ t1,
    float* __restrict__ ss2, float* __restrict__ ss1) {
  int blk = blockIdx.x;
  int b = blk >> 3, ch = blk & 7;
  int s = threadIdx.x;
  const float* p2 = t2 + b * (C_DIM * S_DIM) + (ch * 32) * S_DIM + s;
  const float* p1 = t1 + b * (C_DIM * S_DIM) + (ch * 32) * S_DIM + s;
  float a2 = 0.f, a1 = 0.f;
  #pragma unroll 8
  for (int c = 0; c < 32; ++c) {
    float v2 = p2[c * S_DIM]; a2 += v2 * v2;
    float v1 = p1[c * S_DIM]; a1 += v1 * v1;
  }
  atomicAdd(&ss2[b * S_DIM + s], a2);
  atomicAdd(&ss1[b * S_DIM + s], a1);
}

// K2: G[b,s,t] = sum_c t2n[b,c,s]*t1n[b,c,t]; E = exp(G*20); also writes ET.
// 32x32 output tile per block, C staged in 2 chunks of 128 in LDS.
__global__ __launch_bounds__(256) void gemm_exp_kernel(
    const float* __restrict__ t2, const float* __restrict__ t1,
    const float* __restrict__ ss2, const float* __restrict__ ss1,
    float* __restrict__ E, float* __restrict__ ET) {
  __shared__ float At[128][32];
  __shared__ float Bt[128][32];
  int b  = blockIdx.z;
  int s0 = blockIdx.y * 32;
  int t0 = blockIdx.x * 32;
  int tid = threadIdx.x;
  int sl = tid & 31, cr = tid >> 5;   // load mapping: 8 c-rows per pass
  int tx = tid & 15, ty = tid >> 4;   // compute mapping: 2x2 outputs
  float ascale = 1.0f / fmaxf(sqrtf(ss2[b * S_DIM + s0 + sl]), 1e-12f);
  float bscale = 1.0f / fmaxf(sqrtf(ss1[b * S_DIM + t0 + sl]), 1e-12f);
  const float* base2 = t2 + b * (C_DIM * S_DIM);
  const float* base1 = t1 + b * (C_DIM * S_DIM);
  float acc00 = 0.f, acc01 = 0.f, acc10 = 0.f, acc11 = 0.f;
  for (int cc = 0; cc < 2; ++cc) {
    int c0 = cc * 128;
    #pragma unroll
    for (int i = 0; i < 16; ++i) {
      int c = cr * 16 + i;
      At[c][sl] = base2[(c0 + c) * S_DIM + s0 + sl] * ascale;
      Bt[c][sl] = base1[(c0 + c) * S_DIM + t0 + sl] * bscale;
    }
    __syncthreads();
    #pragma unroll 8
    for (int c = 0; c < 128; ++c) {
      float2 a  = *reinterpret_cast<const float2*>(&At[c][tx * 2]);
      float2 bv = *reinterpret_cast<const float2*>(&Bt[c][ty * 2]);
      acc00 += a.x * bv.x; acc01 += a.x * bv.y;
      acc10 += a.y * bv.x; acc11 += a.y * bv.y;
    }
    __syncthreads();
  }
  int r0 = s0 + tx * 2, c0o = t0 + ty * 2;
  float e00 = expf(acc00 * INV_BW), e01 = expf(acc01 * INV_BW);
  float e10 = expf(acc10 * INV_BW), e11 = expf(acc11 * INV_BW);
  float* Eb  = E  + b * (S_DIM * S_DIM);
  float* ETb = ET + b * (S_DIM * S_DIM);
  *reinterpret_cast<float2*>(&Eb[r0 * S_DIM + c0o])        = make_float2(e00, e01);
  *reinterpret_cast<float2*>(&Eb[(r0 + 1) * S_DIM + c0o])  = make_float2(e10, e11);
  *reinterpret_cast<float2*>(&ETb[c0o * S_DIM + r0])       = make_float2(e00, e10);
  *reinterpret_cast<float2*>(&ETb[(c0o + 1) * S_DIM + r0]) = make_float2(e01, e11);
}

// K3: per-patch histogram of idx over S bins.
__global__ __launch_bounds__(512) void count_kernel(
    const int* __restrict__ idx, float* __restrict__ cnt) {
  __shared__ int c_lds[S_DIM];
  int p = blockIdx.x, t = threadIdx.x;
  c_lds[t] = 0;
  __syncthreads();
  atomicAdd(&c_lds[idx[p * K_DIM + t]], 1);
  __syncthreads();
  cnt[p * S_DIM + t] = (float)c_lds[t];
}

// K4: D1[p,b,t] = sum_s cnt[p,s] * E[b,s,t]  (z=0, M=E)
//     D2[p,b,s] = sum_t cnt[p,t] * E[b,s,t]  (z=1, M=ET)
// 2 patches per block; wave-uniform skip of zero-weight rows.
__global__ __launch_bounds__(512) void denom_kernel(
    const float* __restrict__ E, const float* __restrict__ ET,
    const float* __restrict__ cnt, float* __restrict__ D1, float* __restrict__ D2) {
  int pg = blockIdx.x;              // 0..63
  int b  = blockIdx.y;              // 0..1
  const float* M = blockIdx.z ? ET : E;
  float* Dout    = blockIdx.z ? D2 : D1;
  int t = threadIdx.x;
  __shared__ float w0s[S_DIM], w1s[S_DIM];
  int p0 = pg * 2;
  w0s[t] = cnt[p0 * S_DIM + t];
  w1s[t] = cnt[(p0 + 1) * S_DIM + t];
  __syncthreads();
  const float* Mb = M + b * (S_DIM * S_DIM);
  float a0 = 0.f, a1 = 0.f;
  for (int s = 0; s < S_DIM; ++s) {
    float w0 = w0s[s], w1 = w1s[s];
    if (w0 == 0.f && w1 == 0.f) continue;   // uniform across block
    float e = Mb[s * S_DIM + t];
    a0 += w0 * e; a1 += w1 * e;
  }
  Dout[(p0 * 2 + b) * S_DIM + t]       = a0;
  Dout[((p0 + 1) * 2 + b) * S_DIM + t] = a1;
}

// K5: per-(p,b,k) loss terms, block-reduced to part[p].
__global__ __launch_bounds__(512) void loss_kernel(
    const int* __restrict__ idx, const float* __restrict__ E,
    const float* __restrict__ D1, const float* __restrict__ D2,
    float* __restrict__ part) {
  int p = blockIdx.x, k = threadIdx.x;
  int s = idx[p * K_DIM + k];
  float acc = 0.f;
  #pragma unroll
  for (int b = 0; b < 2; ++b) {
    float pos = E[b * (S_DIM * S_DIM) + s * (S_DIM + 1)];
    float d1  = D1[(p * 2 + b) * S_DIM + s];
    float d2  = D2[(p * 2 + b) * S_DIM + s];
    acc += logf(0.5f * (pos / d1 + pos / d2) + EPS_LOSS);
  }
  for (int o = 32; o; o >>= 1) acc += __shfl_down(acc, o);
  __shared__ float red[8];
  if ((k & 63) == 0) red[k >> 6] = acc;
  __syncthreads();
  if (k == 0) {
    float tsum = 0.f;
    #pragma unroll
    for (int i = 0; i < 8; ++i) tsum += red[i];
    part[p] = tsum;
  }
}

// K6: final mean.
__global__ __launch_bounds__(128) void final_kernel(
    const float* __restrict__ part, float* __restrict__ out) {
  int t = threadIdx.x;
  float v = part[t];
  for (int o = 32; o; o >>= 1) v += __shfl_down(v, o);
  __shared__ float red[2];
  if ((t & 63) == 0) red[t >> 6] = v;
  __syncthreads();
  if (t == 0) out[0] = -(red[0] + red[1]) * (1.0f / (P_DIM * 2.0f * K_DIM));
}

extern "C" void kernel_launch(void* const* d_in, const int* in_sizes, int n_in,
                              void* d_out, int out_size, void* d_ws, size_t ws_size,
                              hipStream_t stream) {
  const float* t2 = (const float*)d_in[0];
  const float* t1 = (const float*)d_in[1];
  const int* idx  = (const int*)d_in[2];
  float* ws = (float*)d_ws;
  float* ss2  = ws + OFF_SS2;
  float* ss1  = ws + OFF_SS1;
  float* E    = ws + OFF_E;
  float* ET   = ws + OFF_ET;
  float* cnt  = ws + OFF_CNT;
  float* D1   = ws + OFF_D1;
  float* D2   = ws + OFF_D2;
  float* part = ws + OFF_PART;

  hipMemsetAsync(ws, 0, 2048 * sizeof(float), stream);  // zero ss2+ss1

  sumsq_kernel<<<16, 512, 0, stream>>>(t2, t1, ss2, ss1);
  gemm_exp_kernel<<<dim3(16, 16, 2), 256, 0, stream>>>(t2, t1, ss2, ss1, E, ET);
  count_kernel<<<P_DIM, 512, 0, stream>>>(idx, cnt);
  denom_kernel<<<dim3(64, 2, 2), 512, 0, stream>>>(E, ET, cnt, D1, D2);
  loss_kernel<<<P_DIM, 512, 0, stream>>>(idx, E, D1, D2, part);
  final_kernel<<<1, 128, 0, stream>>>(part, (float*)d_out);
}

// Round 2
// 48.929 us; speedup vs baseline: 2.8105x; 2.8105x over previous
//
#include <hip/hip_runtime.h>

#define C_DIM 256
#define S_DIM 512
#define P_DIM 128
#define K_DIM 512
#define INV_BW 20.0f
#define EPS_LOSS 1e-5f

// workspace layout (float offsets)
#define OFF_SS2  0                         // [2][512] sumsq of t2 columns
#define OFF_SS1  1024                      // [2][512] sumsq of t1 columns
#define OFF_E    2048                      // [2][512][512] exp(G/bw)
#define OFF_ET   (OFF_E  + 524288)         // [2][512][512] transpose
#define OFF_CNTT (OFF_ET + 524288)         // [512 s][128 p] histogram^T (float)
#define OFF_D1   (OFF_CNTT + 65536)        // [128 p][2 b][512]
#define OFF_D2   (OFF_D1 + 131072)         // [128 p][2 b][512]
#define OFF_PART (OFF_D2 + 131072)         // [128] per-p partial loss sums

// K1: per-(b,s) channel sum-of-squares for both tensors. 32 blocks x 512 thr,
// each block does 16 channels, atomicAdd into zeroed accumulators.
__global__ __launch_bounds__(512) void sumsq_kernel(
    const float* __restrict__ t2, const float* __restrict__ t1,
    float* __restrict__ ss2, float* __restrict__ ss1) {
  int blk = blockIdx.x;
  int b = blk >> 4, ch = blk & 15;
  int s = threadIdx.x;
  const float* p2 = t2 + b * (C_DIM * S_DIM) + (ch * 16) * S_DIM + s;
  const float* p1 = t1 + b * (C_DIM * S_DIM) + (ch * 16) * S_DIM + s;
  float a2 = 0.f, a1 = 0.f;
  #pragma unroll 8
  for (int c = 0; c < 16; ++c) {
    float v2 = p2[c * S_DIM]; a2 += v2 * v2;
    float v1 = p1[c * S_DIM]; a1 += v1 * v1;
  }
  atomicAdd(&ss2[b * S_DIM + s], a2);
  atomicAdd(&ss1[b * S_DIM + s], a1);
}

// K2: G[b,s,t] = sum_c t2n[b,c,s]*t1n[b,c,t]; E = exp(G*20); also writes ET.
// 32x32 output tile per block, C staged in 2 chunks of 128 in LDS.
__global__ __launch_bounds__(256) void gemm_exp_kernel(
    const float* __restrict__ t2, const float* __restrict__ t1,
    const float* __restrict__ ss2, const float* __restrict__ ss1,
    float* __restrict__ E, float* __restrict__ ET) {
  __shared__ float At[128][32];
  __shared__ float Bt[128][32];
  int b  = blockIdx.z;
  int s0 = blockIdx.y * 32;
  int t0 = blockIdx.x * 32;
  int tid = threadIdx.x;
  int sl = tid & 31, cr = tid >> 5;   // load mapping: 8 c-rows per pass
  int tx = tid & 15, ty = tid >> 4;   // compute mapping: 2x2 outputs
  float ascale = 1.0f / fmaxf(sqrtf(ss2[b * S_DIM + s0 + sl]), 1e-12f);
  float bscale = 1.0f / fmaxf(sqrtf(ss1[b * S_DIM + t0 + sl]), 1e-12f);
  const float* base2 = t2 + b * (C_DIM * S_DIM);
  const float* base1 = t1 + b * (C_DIM * S_DIM);
  float acc00 = 0.f, acc01 = 0.f, acc10 = 0.f, acc11 = 0.f;
  for (int cc = 0; cc < 2; ++cc) {
    int c0 = cc * 128;
    #pragma unroll
    for (int i = 0; i < 16; ++i) {
      int c = cr * 16 + i;
      At[c][sl] = base2[(c0 + c) * S_DIM + s0 + sl] * ascale;
      Bt[c][sl] = base1[(c0 + c) * S_DIM + t0 + sl] * bscale;
    }
    __syncthreads();
    #pragma unroll 8
    for (int c = 0; c < 128; ++c) {
      float2 a  = *reinterpret_cast<const float2*>(&At[c][tx * 2]);
      float2 bv = *reinterpret_cast<const float2*>(&Bt[c][ty * 2]);
      acc00 += a.x * bv.x; acc01 += a.x * bv.y;
      acc10 += a.y * bv.x; acc11 += a.y * bv.y;
    }
    __syncthreads();
  }
  int r0 = s0 + tx * 2, c0o = t0 + ty * 2;
  float e00 = expf(acc00 * INV_BW), e01 = expf(acc01 * INV_BW);
  float e10 = expf(acc10 * INV_BW), e11 = expf(acc11 * INV_BW);
  float* Eb  = E  + b * (S_DIM * S_DIM);
  float* ETb = ET + b * (S_DIM * S_DIM);
  *reinterpret_cast<float2*>(&Eb[r0 * S_DIM + c0o])        = make_float2(e00, e01);
  *reinterpret_cast<float2*>(&Eb[(r0 + 1) * S_DIM + c0o])  = make_float2(e10, e11);
  *reinterpret_cast<float2*>(&ETb[c0o * S_DIM + r0])       = make_float2(e00, e10);
  *reinterpret_cast<float2*>(&ETb[(c0o + 1) * S_DIM + r0]) = make_float2(e01, e11);
}

// K3: per-patch histogram of idx over S bins, written TRANSPOSED: cntT[s][p].
__global__ __launch_bounds__(512) void count_kernel(
    const int* __restrict__ idx, float* __restrict__ cntT) {
  __shared__ int c_lds[S_DIM];
  int p = blockIdx.x, t = threadIdx.x;
  c_lds[t] = 0;
  __syncthreads();
  atomicAdd(&c_lds[idx[p * K_DIM + t]], 1);
  __syncthreads();
  cntT[t * P_DIM + p] = (float)c_lds[t];
}

// K4: uniform NN GEMM: D_z[p, col] = sum_k cntT[k][p] * M_z[k, col]
//   z=0: M=E  -> D1[p,b,t];  z=1: M=ET -> D2[p,b,s]
// BM=128 (all p), BN=16, BK=32; 256 threads, 4p x 2col per thread.
// grid (32 col-tiles, 2 b, 2 z) = 128 blocks. Prefetch pipeline global->reg->LDS.
#define BKD 32
__global__ __launch_bounds__(256) void denom_gemm_kernel(
    const float* __restrict__ E, const float* __restrict__ ET,
    const float* __restrict__ cntT, float* __restrict__ D1, float* __restrict__ D2) {
  __shared__ alignas(16) float Ws[BKD][132];  // [k][p], padded
  __shared__ alignas(16) float Ms[BKD][16];   // [k][col]
  int c0 = blockIdx.x * 16;
  int b  = blockIdx.y;
  const float* M = (blockIdx.z ? ET : E) + b * (S_DIM * S_DIM);
  float* Dout    = blockIdx.z ? D2 : D1;
  int tid = threadIdx.x;
  int pg = tid >> 3;        // 0..31 -> p0 = pg*4
  int tg = tid & 7;         // 0..7  -> cols c0 + tg*2, +1
  // staging indices
  int wk = tid >> 5;        // 0..7  (Ws rows wk, wk+8, wk+16, wk+24)
  int wp = (tid & 31) * 4;  // float4 column in Ws
  int mk = tid >> 4;        // 0..15 (Ms rows mk, mk+16)
  int mt = tid & 15;
  float4 wr0, wr1, wr2, wr3;
  float mr0, mr1;
  auto load_chunk = [&](int k0) {
    wr0 = *reinterpret_cast<const float4*>(&cntT[(k0 + wk)      * P_DIM + wp]);
    wr1 = *reinterpret_cast<const float4*>(&cntT[(k0 + wk + 8)  * P_DIM + wp]);
    wr2 = *reinterpret_cast<const float4*>(&cntT[(k0 + wk + 16) * P_DIM + wp]);
    wr3 = *reinterpret_cast<const float4*>(&cntT[(k0 + wk + 24) * P_DIM + wp]);
    mr0 = M[(k0 + mk)      * S_DIM + c0 + mt];
    mr1 = M[(k0 + mk + 16) * S_DIM + c0 + mt];
  };
  float acc[4][2] = {};
  load_chunk(0);
  for (int kc = 0; kc < S_DIM / BKD; ++kc) {
    __syncthreads();
    *reinterpret_cast<float4*>(&Ws[wk][wp])      = wr0;
    *reinterpret_cast<float4*>(&Ws[wk + 8][wp])  = wr1;
    *reinterpret_cast<float4*>(&Ws[wk + 16][wp]) = wr2;
    *reinterpret_cast<float4*>(&Ws[wk + 24][wp]) = wr3;
    Ms[mk][mt]      = mr0;
    Ms[mk + 16][mt] = mr1;
    __syncthreads();
    if (kc + 1 < S_DIM / BKD) load_chunk((kc + 1) * BKD);
    #pragma unroll
    for (int k = 0; k < BKD; ++k) {
      float4 w = *reinterpret_cast<const float4*>(&Ws[k][pg * 4]);
      float2 m = *reinterpret_cast<const float2*>(&Ms[k][tg * 2]);
      acc[0][0] += w.x * m.x; acc[0][1] += w.x * m.y;
      acc[1][0] += w.y * m.x; acc[1][1] += w.y * m.y;
      acc[2][0] += w.z * m.x; acc[2][1] += w.z * m.y;
      acc[3][0] += w.w * m.x; acc[3][1] += w.w * m.y;
    }
  }
  #pragma unroll
  for (int i = 0; i < 4; ++i) {
    int p = pg * 4 + i;
    *reinterpret_cast<float2*>(&Dout[(p * 2 + b) * S_DIM + c0 + tg * 2]) =
        make_float2(acc[i][0], acc[i][1]);
  }
}

// K5: per-(p,b,k) loss terms, block-reduced to part[p].
__global__ __launch_bounds__(512) void loss_kernel(
    const int* __restrict__ idx, const float* __restrict__ E,
    const float* __restrict__ D1, const float* __restrict__ D2,
    float* __restrict__ part) {
  int p = blockIdx.x, k = threadIdx.x;
  int s = idx[p * K_DIM + k];
  float acc = 0.f;
  #pragma unroll
  for (int b = 0; b < 2; ++b) {
    float pos = E[b * (S_DIM * S_DIM) + s * (S_DIM + 1)];
    float d1  = D1[(p * 2 + b) * S_DIM + s];
    float d2  = D2[(p * 2 + b) * S_DIM + s];
    acc += logf(0.5f * (pos / d1 + pos / d2) + EPS_LOSS);
  }
  for (int o = 32; o; o >>= 1) acc += __shfl_down(acc, o);
  __shared__ float red[8];
  if ((k & 63) == 0) red[k >> 6] = acc;
  __syncthreads();
  if (k == 0) {
    float tsum = 0.f;
    #pragma unroll
    for (int i = 0; i < 8; ++i) tsum += red[i];
    part[p] = tsum;
  }
}

// K6: final mean.
__global__ __launch_bounds__(128) void final_kernel(
    const float* __restrict__ part, float* __restrict__ out) {
  int t = threadIdx.x;
  float v = part[t];
  for (int o = 32; o; o >>= 1) v += __shfl_down(v, o);
  __shared__ float red[2];
  if ((t & 63) == 0) red[t >> 6] = v;
  __syncthreads();
  if (t == 0) out[0] = -(red[0] + red[1]) * (1.0f / (P_DIM * 2.0f * K_DIM));
}

extern "C" void kernel_launch(void* const* d_in, const int* in_sizes, int n_in,
                              void* d_out, int out_size, void* d_ws, size_t ws_size,
                              hipStream_t stream) {
  const float* t2 = (const float*)d_in[0];
  const float* t1 = (const float*)d_in[1];
  const int* idx  = (const int*)d_in[2];
  float* ws = (float*)d_ws;
  float* ss2  = ws + OFF_SS2;
  float* ss1  = ws + OFF_SS1;
  float* E    = ws + OFF_E;
  float* ET   = ws + OFF_ET;
  float* cntT = ws + OFF_CNTT;
  float* D1   = ws + OFF_D1;
  float* D2   = ws + OFF_D2;
  float* part = ws + OFF_PART;

  hipMemsetAsync(ws, 0, 2048 * sizeof(float), stream);  // zero ss2+ss1

  sumsq_kernel<<<32, 512, 0, stream>>>(t2, t1, ss2, ss1);
  gemm_exp_kernel<<<dim3(16, 16, 2), 256, 0, stream>>>(t2, t1, ss2, ss1, E, ET);
  count_kernel<<<P_DIM, 512, 0, stream>>>(idx, cntT);
  denom_gemm_kernel<<<dim3(32, 2, 2), 256, 0, stream>>>(E, ET, cntT, D1, D2);
  loss_kernel<<<P_DIM, 512, 0, stream>>>(idx, E, D1, D2, part);
  final_kernel<<<1, 128, 0, stream>>>(part, (float*)d_out);
}

// Round 3
// 47.673 us; speedup vs baseline: 2.8845x; 1.0264x over previous
//
#include <hip/hip_runtime.h>

#define C_DIM 256
#define S_DIM 512
#define P_DIM 128
#define K_DIM 512
#define INV_BW 20.0f
#define EPS_LOSS 1e-5f

// workspace layout (float offsets) — every cell overwritten each call, no zeroing needed
#define OFF_P2PART 0                        // [2][16][512] partial sumsq of t2
#define OFF_P1PART 16384                    // [2][16][512] partial sumsq of t1
#define OFF_E      32768                    // [2][512][512] exp(G/bw)
#define OFF_ET     (OFF_E  + 524288)        // [2][512][512] transpose
#define OFF_CNTT   (OFF_ET + 524288)        // [512 s][128 p] histogram^T (float)
#define OFF_D1     (OFF_CNTT + 65536)       // [128 p][2 b][512]
#define OFF_D2     (OFF_D1 + 131072)        // [128 p][2 b][512]
#define OFF_PART   (OFF_D2 + 131072)        // [128] per-p partial loss sums
#define OFF_TICKET (OFF_PART + 128)         // [1] int ticket (zeroed in K1 each call)

// K1: blocks 0..31  -> partial channel sum-of-squares (16 channels each, no atomics)
//     blocks 32..159 -> per-patch histogram of idx, transposed write cntT[s][p]
__global__ __launch_bounds__(512) void pre_kernel(
    const float* __restrict__ t2, const float* __restrict__ t1,
    const int* __restrict__ idx,
    float* __restrict__ p2part, float* __restrict__ p1part,
    float* __restrict__ cntT, int* __restrict__ ticket) {
  int blk = blockIdx.x, t = threadIdx.x;
  if (blk < 32) {
    int b = blk >> 4, g = blk & 15;
    const float* p2 = t2 + b * (C_DIM * S_DIM) + (g * 16) * S_DIM + t;
    const float* p1 = t1 + b * (C_DIM * S_DIM) + (g * 16) * S_DIM + t;
    float a2 = 0.f, a1 = 0.f;
    #pragma unroll
    for (int c = 0; c < 16; ++c) {
      float v2 = p2[c * S_DIM]; a2 += v2 * v2;
      float v1 = p1[c * S_DIM]; a1 += v1 * v1;
    }
    p2part[(b * 16 + g) * S_DIM + t] = a2;
    p1part[(b * 16 + g) * S_DIM + t] = a1;
  } else {
    __shared__ int c_lds[S_DIM];
    int p = blk - 32;
    if (blk == 32 && t == 0) *ticket = 0;   // re-arm last-arriver each call
    c_lds[t] = 0;
    __syncthreads();
    atomicAdd(&c_lds[idx[p * K_DIM + t]], 1);
    __syncthreads();
    cntT[t * P_DIM + p] = (float)c_lds[t];
  }
}

// K2: G[b,s,t] = sum_c t2n[b,c,s]*t1n[b,c,t]; E = exp(G*20); also writes ET.
// Per-block: reduce the 16 sumsq partials into 32 ascale + 32 bscale (threads 0..63),
// then 32x32 output tile, C staged in 2 chunks of 128 in LDS.
__global__ __launch_bounds__(256) void gemm_exp_kernel(
    const float* __restrict__ t2, const float* __restrict__ t1,
    const float* __restrict__ p2part, const float* __restrict__ p1part,
    float* __restrict__ E, float* __restrict__ ET) {
  __shared__ float At[128][32];
  __shared__ float Bt[128][32];
  __shared__ float As[32], Bs[32];
  int b  = blockIdx.z;
  int s0 = blockIdx.y * 32;
  int t0 = blockIdx.x * 32;
  int tid = threadIdx.x;
  if (tid < 64) {
    int lane = tid & 31;
    const float* src = (tid < 32) ? p2part : p1part;
    int col = ((tid < 32) ? s0 : t0) + lane;
    float ss = 0.f;
    #pragma unroll
    for (int j = 0; j < 16; ++j) ss += src[(b * 16 + j) * S_DIM + col];
    float sc = 1.0f / fmaxf(sqrtf(ss), 1e-12f);
    if (tid < 32) As[lane] = sc; else Bs[lane] = sc;
  }
  __syncthreads();
  int sl = tid & 31, cr = tid >> 5;   // load mapping: 8 c-rows per pass
  int tx = tid & 15, ty = tid >> 4;   // compute mapping: 2x2 outputs
  float ascale = As[sl], bscale = Bs[sl];
  const float* base2 = t2 + b * (C_DIM * S_DIM);
  const float* base1 = t1 + b * (C_DIM * S_DIM);
  float acc00 = 0.f, acc01 = 0.f, acc10 = 0.f, acc11 = 0.f;
  for (int cc = 0; cc < 2; ++cc) {
    int c0 = cc * 128;
    #pragma unroll
    for (int i = 0; i < 16; ++i) {
      int c = cr * 16 + i;
      At[c][sl] = base2[(c0 + c) * S_DIM + s0 + sl] * ascale;
      Bt[c][sl] = base1[(c0 + c) * S_DIM + t0 + sl] * bscale;
    }
    __syncthreads();
    #pragma unroll 8
    for (int c = 0; c < 128; ++c) {
      float2 a  = *reinterpret_cast<const float2*>(&At[c][tx * 2]);
      float2 bv = *reinterpret_cast<const float2*>(&Bt[c][ty * 2]);
      acc00 += a.x * bv.x; acc01 += a.x * bv.y;
      acc10 += a.y * bv.x; acc11 += a.y * bv.y;
    }
    __syncthreads();
  }
  int r0 = s0 + tx * 2, c0o = t0 + ty * 2;
  float e00 = expf(acc00 * INV_BW), e01 = expf(acc01 * INV_BW);
  float e10 = expf(acc10 * INV_BW), e11 = expf(acc11 * INV_BW);
  float* Eb  = E  + b * (S_DIM * S_DIM);
  float* ETb = ET + b * (S_DIM * S_DIM);
  *reinterpret_cast<float2*>(&Eb[r0 * S_DIM + c0o])        = make_float2(e00, e01);
  *reinterpret_cast<float2*>(&Eb[(r0 + 1) * S_DIM + c0o])  = make_float2(e10, e11);
  *reinterpret_cast<float2*>(&ETb[c0o * S_DIM + r0])       = make_float2(e00, e10);
  *reinterpret_cast<float2*>(&ETb[(c0o + 1) * S_DIM + r0]) = make_float2(e01, e11);
}

// K3: uniform NN GEMM: D_z[p, col] = sum_k cntT[k][p] * M_z[k, col]
//   z=0: M=E  -> D1[p,b,t];  z=1: M=ET -> D2[p,b,s]
// BM=128 (all p), BN=16, BK=32; 256 threads, 4p x 2col per thread.
#define BKD 32
__global__ __launch_bounds__(256) void denom_gemm_kernel(
    const float* __restrict__ E, const float* __restrict__ ET,
    const float* __restrict__ cntT, float* __restrict__ D1, float* __restrict__ D2) {
  __shared__ alignas(16) float Ws[BKD][132];  // [k][p], padded
  __shared__ alignas(16) float Ms[BKD][16];   // [k][col]
  int c0 = blockIdx.x * 16;
  int b  = blockIdx.y;
  const float* M = (blockIdx.z ? ET : E) + b * (S_DIM * S_DIM);
  float* Dout    = blockIdx.z ? D2 : D1;
  int tid = threadIdx.x;
  int pg = tid >> 3;        // 0..31 -> p0 = pg*4
  int tg = tid & 7;         // 0..7  -> cols c0 + tg*2, +1
  int wk = tid >> 5;        // 0..7  (Ws rows wk, wk+8, wk+16, wk+24)
  int wp = (tid & 31) * 4;  // float4 column in Ws
  int mk = tid >> 4;        // 0..15 (Ms rows mk, mk+16)
  int mt = tid & 15;
  float4 wr0, wr1, wr2, wr3;
  float mr0, mr1;
  auto load_chunk = [&](int k0) {
    wr0 = *reinterpret_cast<const float4*>(&cntT[(k0 + wk)      * P_DIM + wp]);
    wr1 = *reinterpret_cast<const float4*>(&cntT[(k0 + wk + 8)  * P_DIM + wp]);
    wr2 = *reinterpret_cast<const float4*>(&cntT[(k0 + wk + 16) * P_DIM + wp]);
    wr3 = *reinterpret_cast<const float4*>(&cntT[(k0 + wk + 24) * P_DIM + wp]);
    mr0 = M[(k0 + mk)      * S_DIM + c0 + mt];
    mr1 = M[(k0 + mk + 16) * S_DIM + c0 + mt];
  };
  float acc[4][2] = {};
  load_chunk(0);
  for (int kc = 0; kc < S_DIM / BKD; ++kc) {
    __syncthreads();
    *reinterpret_cast<float4*>(&Ws[wk][wp])      = wr0;
    *reinterpret_cast<float4*>(&Ws[wk + 8][wp])  = wr1;
    *reinterpret_cast<float4*>(&Ws[wk + 16][wp]) = wr2;
    *reinterpret_cast<float4*>(&Ws[wk + 24][wp]) = wr3;
    Ms[mk][mt]      = mr0;
    Ms[mk + 16][mt] = mr1;
    __syncthreads();
    if (kc + 1 < S_DIM / BKD) load_chunk((kc + 1) * BKD);
    #pragma unroll
    for (int k = 0; k < BKD; ++k) {
      float4 w = *reinterpret_cast<const float4*>(&Ws[k][pg * 4]);
      float2 m = *reinterpret_cast<const float2*>(&Ms[k][tg * 2]);
      acc[0][0] += w.x * m.x; acc[0][1] += w.x * m.y;
      acc[1][0] += w.y * m.x; acc[1][1] += w.y * m.y;
      acc[2][0] += w.z * m.x; acc[2][1] += w.z * m.y;
      acc[3][0] += w.w * m.x; acc[3][1] += w.w * m.y;
    }
  }
  #pragma unroll
  for (int i = 0; i < 4; ++i) {
    int p = pg * 4 + i;
    *reinterpret_cast<float2*>(&Dout[(p * 2 + b) * S_DIM + c0 + tg * 2]) =
        make_float2(acc[i][0], acc[i][1]);
  }
}

// K4: per-(p,b,k) loss terms, block-reduced; last-arriving block does the final
// deterministic tree reduction over the 128 partials and writes the scalar out.
__global__ __launch_bounds__(512) void loss_final_kernel(
    const int* __restrict__ idx, const float* __restrict__ E,
    const float* __restrict__ D1, const float* __restrict__ D2,
    float* __restrict__ part, int* __restrict__ ticket, float* __restrict__ out) {
  int p = blockIdx.x, k = threadIdx.x;
  int s = idx[p * K_DIM + k];
  float acc = 0.f;
  #pragma unroll
  for (int b = 0; b < 2; ++b) {
    float pos = E[b * (S_DIM * S_DIM) + s * (S_DIM + 1)];
    float d1  = D1[(p * 2 + b) * S_DIM + s];
    float d2  = D2[(p * 2 + b) * S_DIM + s];
    acc += logf(0.5f * (pos / d1 + pos / d2) + EPS_LOSS);
  }
  for (int o = 32; o; o >>= 1) acc += __shfl_down(acc, o);
  __shared__ float red[8];
  __shared__ int lastflag;
  if ((k & 63) == 0) red[k >> 6] = acc;
  __syncthreads();
  if (k == 0) {
    float tsum = 0.f;
    #pragma unroll
    for (int i = 0; i < 8; ++i) tsum += red[i];
    atomicExch(&part[p], tsum);        // device-coherent store
    __threadfence();
    int old = atomicAdd(ticket, 1);
    lastflag = (old == P_DIM - 1);
  }
  __syncthreads();
  if (lastflag) {
    __threadfence();
    float v = (k < P_DIM) ? atomicAdd(&part[k], 0.0f) : 0.0f;  // coherent read
    for (int o = 32; o; o >>= 1) v += __shfl_down(v, o);
    __shared__ float red2[8];
    if ((k & 63) == 0) red2[k >> 6] = v;
    __syncthreads();
    if (k == 0) {
      float tsum = 0.f;
      #pragma unroll
      for (int i = 0; i < 8; ++i) tsum += red2[i];
      out[0] = -tsum * (1.0f / (P_DIM * 2.0f * K_DIM));
    }
  }
}

extern "C" void kernel_launch(void* const* d_in, const int* in_sizes, int n_in,
                              void* d_out, int out_size, void* d_ws, size_t ws_size,
                              hipStream_t stream) {
  const float* t2 = (const float*)d_in[0];
  const float* t1 = (const float*)d_in[1];
  const int* idx  = (const int*)d_in[2];
  float* ws = (float*)d_ws;
  float* p2part = ws + OFF_P2PART;
  float* p1part = ws + OFF_P1PART;
  float* E      = ws + OFF_E;
  float* ET     = ws + OFF_ET;
  float* cntT   = ws + OFF_CNTT;
  float* D1     = ws + OFF_D1;
  float* D2     = ws + OFF_D2;
  float* part   = ws + OFF_PART;
  int*   ticket = (int*)(ws + OFF_TICKET);

  pre_kernel<<<160, 512, 0, stream>>>(t2, t1, idx, p2part, p1part, cntT, ticket);
  gemm_exp_kernel<<<dim3(16, 16, 2), 256, 0, stream>>>(t2, t1, p2part, p1part, E, ET);
  denom_gemm_kernel<<<dim3(32, 2, 2), 256, 0, stream>>>(E, ET, cntT, D1, D2);
  loss_final_kernel<<<P_DIM, 512, 0, stream>>>(idx, E, D1, D2, part, ticket, (float*)d_out);
}

// Round 4
// 35.051 us; speedup vs baseline: 3.9233x; 1.3601x over previous
//
#include <hip/hip_runtime.h>

typedef __attribute__((ext_vector_type(8))) short bf16x8;
typedef __attribute__((ext_vector_type(4))) float f32x4;

#define C_DIM 256
#define S_DIM 512
#define P_DIM 128
#define K_DIM 512
#define INV_BW 20.0f
#define EPS_LOSS 1e-5f

// workspace layout (float offsets) — every cell overwritten each call
#define OFF_P2PART 0                 // [2][16][512] partial sumsq of t2
#define OFF_P1PART 16384             // [2][16][512] partial sumsq of t1
#define OFF_DIAG   32768             // [2][512] fp32 diagonal of E
#define OFF_CNTBF  33792             // [128 p][512 s] bf16 histogram (32768 float slots)
#define OFF_EBF    66560             // [2][512][512] bf16 E
#define OFF_ETBF   328704            // [2][512][512] bf16 E^T
#define OFF_D1P    590848            // [2 h][128 p][2 b][512] fp32 partial
#define OFF_D2P    852992            // [2 h][128 p][2 b][512] fp32 partial
#define OFF_PART   1115136           // [128]
#define OFF_TICKET 1115264           // [1] int

__device__ inline ushort f2bf(float f) {   // RNE float->bf16 (inputs finite)
  union { float f; uint u; } v; v.f = f;
  return (ushort)((v.u + 0x7FFF + ((v.u >> 16) & 1)) >> 16);
}

// K1: blocks 0..31  -> partial channel sum-of-squares (no atomics)
//     blocks 32..159 -> per-patch histogram, written bf16 row-major cnt[p][s]
__global__ __launch_bounds__(512) void pre_kernel(
    const float* __restrict__ t2, const float* __restrict__ t1,
    const int* __restrict__ idx,
    float* __restrict__ p2part, float* __restrict__ p1part,
    ushort* __restrict__ cntbf, int* __restrict__ ticket) {
  int blk = blockIdx.x, t = threadIdx.x;
  if (blk < 32) {
    int b = blk >> 4, g = blk & 15;
    const float* p2 = t2 + b * (C_DIM * S_DIM) + (g * 16) * S_DIM + t;
    const float* p1 = t1 + b * (C_DIM * S_DIM) + (g * 16) * S_DIM + t;
    float a2 = 0.f, a1 = 0.f;
    #pragma unroll
    for (int c = 0; c < 16; ++c) {
      float v2 = p2[c * S_DIM]; a2 += v2 * v2;
      float v1 = p1[c * S_DIM]; a1 += v1 * v1;
    }
    p2part[(b * 16 + g) * S_DIM + t] = a2;
    p1part[(b * 16 + g) * S_DIM + t] = a1;
  } else {
    __shared__ int c_lds[S_DIM];
    int p = blk - 32;
    if (blk == 32 && t == 0) *ticket = 0;   // re-arm last-arriver each call
    c_lds[t] = 0;
    __syncthreads();
    atomicAdd(&c_lds[idx[p * K_DIM + t]], 1);
    __syncthreads();
    cntbf[p * S_DIM + t] = f2bf((float)c_lds[t]);   // counts exact in bf16
  }
}

// K2: G[b,s,t] = sum_c t2n*t1n; writes Ebf=bf16(exp(G*20)), ETbf, and fp32 diag.
__global__ __launch_bounds__(256) void gemm_exp_kernel(
    const float* __restrict__ t2, const float* __restrict__ t1,
    const float* __restrict__ p2part, const float* __restrict__ p1part,
    ushort* __restrict__ Ebf, ushort* __restrict__ ETbf,
    float* __restrict__ diag) {
  __shared__ float At[128][32];
  __shared__ float Bt[128][32];
  __shared__ float As[32], Bs[32];
  int b  = blockIdx.z;
  int s0 = blockIdx.y * 32;
  int t0 = blockIdx.x * 32;
  int tid = threadIdx.x;
  if (tid < 64) {
    int lane = tid & 31;
    const float* src = (tid < 32) ? p2part : p1part;
    int col = ((tid < 32) ? s0 : t0) + lane;
    float ss = 0.f;
    #pragma unroll
    for (int j = 0; j < 16; ++j) ss += src[(b * 16 + j) * S_DIM + col];
    float sc = 1.0f / fmaxf(sqrtf(ss), 1e-12f);
    if (tid < 32) As[lane] = sc; else Bs[lane] = sc;
  }
  __syncthreads();
  int sl = tid & 31, cr = tid >> 5;
  int tx = tid & 15, ty = tid >> 4;
  float ascale = As[sl], bscale = Bs[sl];
  const float* base2 = t2 + b * (C_DIM * S_DIM);
  const float* base1 = t1 + b * (C_DIM * S_DIM);
  float acc00 = 0.f, acc01 = 0.f, acc10 = 0.f, acc11 = 0.f;
  for (int cc = 0; cc < 2; ++cc) {
    int c0 = cc * 128;
    #pragma unroll
    for (int i = 0; i < 16; ++i) {
      int c = cr * 16 + i;
      At[c][sl] = base2[(c0 + c) * S_DIM + s0 + sl] * ascale;
      Bt[c][sl] = base1[(c0 + c) * S_DIM + t0 + sl] * bscale;
    }
    __syncthreads();
    #pragma unroll 8
    for (int c = 0; c < 128; ++c) {
      float2 a  = *reinterpret_cast<const float2*>(&At[c][tx * 2]);
      float2 bv = *reinterpret_cast<const float2*>(&Bt[c][ty * 2]);
      acc00 += a.x * bv.x; acc01 += a.x * bv.y;
      acc10 += a.y * bv.x; acc11 += a.y * bv.y;
    }
    __syncthreads();
  }
  int r0 = s0 + tx * 2, c0o = t0 + ty * 2;
  float e00 = expf(acc00 * INV_BW), e01 = expf(acc01 * INV_BW);
  float e10 = expf(acc10 * INV_BW), e11 = expf(acc11 * INV_BW);
  ushort* Eb  = Ebf  + b * (S_DIM * S_DIM);
  ushort* ETb = ETbf + b * (S_DIM * S_DIM);
  *reinterpret_cast<uint*>(&Eb[r0 * S_DIM + c0o]) =
      (uint)f2bf(e00) | ((uint)f2bf(e01) << 16);
  *reinterpret_cast<uint*>(&Eb[(r0 + 1) * S_DIM + c0o]) =
      (uint)f2bf(e10) | ((uint)f2bf(e11) << 16);
  *reinterpret_cast<uint*>(&ETb[c0o * S_DIM + r0]) =
      (uint)f2bf(e00) | ((uint)f2bf(e10) << 16);
  *reinterpret_cast<uint*>(&ETb[(c0o + 1) * S_DIM + r0]) =
      (uint)f2bf(e01) | ((uint)f2bf(e11) << 16);
  if (blockIdx.x == blockIdx.y && tx == ty) {   // diagonal lives in this tile
    diag[b * S_DIM + r0]     = e00;
    diag[b * S_DIM + r0 + 1] = e11;
  }
}

// K3: MFMA denominators. D1[p,b,t] = sum_s cnt[p,s]E[b,s,t] (B-frag from ETbf),
//     D2[p,b,s] = sum_t cnt[p,t]E[b,s,t] (B-frag from Ebf). K split in 2 halves.
// 2048 wave-jobs = 2h x 2z x 2b x 8m x 32n; fragments loaded direct from L2.
__global__ __launch_bounds__(256) void denom_mfma_kernel(
    const ushort* __restrict__ Ebf, const ushort* __restrict__ ETbf,
    const ushort* __restrict__ cntbf,
    float* __restrict__ D1p, float* __restrict__ D2p) {
  int wave = threadIdx.x >> 6, lane = threadIdx.x & 63;
  int job = blockIdx.x * 4 + wave;          // 0..2047
  int n = job & 31, m = (job >> 5) & 7, b = (job >> 8) & 1;
  int z = (job >> 9) & 1, h = job >> 10;
  int m0 = m * 16, col0 = n * 16;
  const ushort* Bmat = (z ? Ebf : ETbf) + b * (S_DIM * S_DIM);
  float* Dp = (z ? D2p : D1p) + h * (P_DIM * 2 * S_DIM);
  int lr = lane & 15, lo = lane >> 4;       // row-in-tile, k-octet
  const ushort* aptr = cntbf + (m0 + lr) * S_DIM + h * 256 + lo * 8;
  const ushort* bptr = Bmat + (col0 + lr) * S_DIM + h * 256 + lo * 8;
  f32x4 acc = {0.f, 0.f, 0.f, 0.f};
  #pragma unroll
  for (int k = 0; k < 8; ++k) {
    bf16x8 af = *reinterpret_cast<const bf16x8*>(aptr + k * 32);
    bf16x8 bfv = *reinterpret_cast<const bf16x8*>(bptr + k * 32);
    acc = __builtin_amdgcn_mfma_f32_16x16x32_bf16(af, bfv, acc, 0, 0, 0);
  }
  #pragma unroll
  for (int r = 0; r < 4; ++r) {
    int p = m0 + lo * 4 + r;                // C/D: row=(lane>>4)*4+reg, col=lane&15
    Dp[(p * 2 + b) * S_DIM + col0 + lr] = acc[r];
  }
}

// K4: loss terms + last-arriver final reduction.
__global__ __launch_bounds__(512) void loss_final_kernel(
    const int* __restrict__ idx, const float* __restrict__ diag,
    const float* __restrict__ D1p, const float* __restrict__ D2p,
    float* __restrict__ part, int* __restrict__ ticket, float* __restrict__ out) {
  const int HOFF = P_DIM * 2 * S_DIM;
  int p = blockIdx.x, k = threadIdx.x;
  int s = idx[p * K_DIM + k];
  float acc = 0.f;
  #pragma unroll
  for (int b = 0; b < 2; ++b) {
    float pos = diag[b * S_DIM + s];
    int o = (p * 2 + b) * S_DIM + s;
    float d1 = D1p[o] + D1p[HOFF + o];
    float d2 = D2p[o] + D2p[HOFF + o];
    acc += logf(0.5f * (pos / d1 + pos / d2) + EPS_LOSS);
  }
  for (int o = 32; o; o >>= 1) acc += __shfl_down(acc, o);
  __shared__ float red[8];
  __shared__ int lastflag;
  if ((k & 63) == 0) red[k >> 6] = acc;
  __syncthreads();
  if (k == 0) {
    float tsum = 0.f;
    #pragma unroll
    for (int i = 0; i < 8; ++i) tsum += red[i];
    atomicExch(&part[p], tsum);
    __threadfence();
    int old = atomicAdd(ticket, 1);
    lastflag = (old == P_DIM - 1);
  }
  __syncthreads();
  if (lastflag) {
    __threadfence();
    float v = (k < P_DIM) ? atomicAdd(&part[k], 0.0f) : 0.0f;
    for (int o = 32; o; o >>= 1) v += __shfl_down(v, o);
    __shared__ float red2[8];
    if ((k & 63) == 0) red2[k >> 6] = v;
    __syncthreads();
    if (k == 0) {
      float tsum = 0.f;
      #pragma unroll
      for (int i = 0; i < 8; ++i) tsum += red2[i];
      out[0] = -tsum * (1.0f / (P_DIM * 2.0f * K_DIM));
    }
  }
}

extern "C" void kernel_launch(void* const* d_in, const int* in_sizes, int n_in,
                              void* d_out, int out_size, void* d_ws, size_t ws_size,
                              hipStream_t stream) {
  const float* t2 = (const float*)d_in[0];
  const float* t1 = (const float*)d_in[1];
  const int* idx  = (const int*)d_in[2];
  float* ws = (float*)d_ws;
  float*  p2part = ws + OFF_P2PART;
  float*  p1part = ws + OFF_P1PART;
  float*  diag   = ws + OFF_DIAG;
  ushort* cntbf  = (ushort*)(ws + OFF_CNTBF);
  ushort* Ebf    = (ushort*)(ws + OFF_EBF);
  ushort* ETbf   = (ushort*)(ws + OFF_ETBF);
  float*  D1p    = ws + OFF_D1P;
  float*  D2p    = ws + OFF_D2P;
  float*  part   = ws + OFF_PART;
  int*    ticket = (int*)(ws + OFF_TICKET);

  pre_kernel<<<160, 512, 0, stream>>>(t2, t1, idx, p2part, p1part, cntbf, ticket);
  gemm_exp_kernel<<<dim3(16, 16, 2), 256, 0, stream>>>(t2, t1, p2part, p1part,
                                                       Ebf, ETbf, diag);
  denom_mfma_kernel<<<512, 256, 0, stream>>>(Ebf, ETbf, cntbf, D1p, D2p);
  loss_final_kernel<<<P_DIM, 512, 0, stream>>>(idx, diag, D1p, D2p, part, ticket,
                                               (float*)d_out);
}

// Round 5
// 30.662 us; speedup vs baseline: 4.4849x; 1.1431x over previous
//
#include <hip/hip_runtime.h>

typedef __attribute__((ext_vector_type(8))) short bf16x8;
typedef __attribute__((ext_vector_type(4))) float f32x4;
typedef __attribute__((ext_vector_type(4))) ushort u16x4;

#define C_DIM 256
#define S_DIM 512
#define P_DIM 128
#define K_DIM 512
#define INV_BW 20.0f
#define EPS_LOSS 1e-5f

// ws layout (float offsets). D1P aliases T2BF+T1BF (dead after gemm_exp).
#define OFF_SS2    0          // [2][512] fp32
#define OFF_SS1    1024       // [2][512] fp32
#define OFF_DIAG   2048       // [2][512] fp32
#define OFF_CNTBF  3072       // [128 p][512 s] bf16 (32768 float slots)
#define OFF_T2BF   35840      // [2][512 s][256 c] bf16 (131072 float slots)
#define OFF_T1BF   166912     // [2][512 s][256 c] bf16 (131072 float slots)
#define OFF_EBF    297984     // [2][512][512] bf16 (262144 float slots)
#define OFF_ETBF   560128     // [2][512][512] bf16
#define OFF_D1P    35840      // ALIAS over T2BF/T1BF: [2 h][128][2 b][512] fp32
#define OFF_D2P    822272     // [2 h][128][2 b][512] fp32
#define OFF_PART   1084416    // [128]
#define OFF_TICKET 1084544    // [1] int

__device__ inline ushort f2bf(float f) {   // RNE float->bf16 (finite inputs)
  union { float f; uint u; } v; v.f = f;
  return (ushort)((v.u + 0x7FFF + ((v.u >> 16) & 1)) >> 16);
}

// K1: blocks 0..63   -> sumsq + bf16 transpose of t2,t1 (16 s x 256 c per block)
//     blocks 64..191 -> per-patch histogram -> bf16 cnt[p][s]
#define TP 260   // LDS pitch in ushorts (520 B: 8B-aligned rows, 2-way write banks)
__global__ __launch_bounds__(256) void pre_kernel(
    const float* __restrict__ t2, const float* __restrict__ t1,
    const int* __restrict__ idx,
    float* __restrict__ ss2, float* __restrict__ ss1,
    ushort* __restrict__ t2bfT, ushort* __restrict__ t1bfT,
    ushort* __restrict__ cntbf, int* __restrict__ ticket) {
  int blk = blockIdx.x, tid = threadIdx.x;
  if (blk < 64) {
    __shared__ ushort tl[16][TP];
    __shared__ float ps[16][17];
    int b = blk >> 5, stile = blk & 31;
    int s0 = stile * 16;
    int ls = tid & 15, cg = tid >> 4;     // s-offset, c-group
    int wv = tid >> 6, ln = tid & 63;
    #pragma unroll
    for (int tt = 0; tt < 2; ++tt) {
      const float* src = (tt ? t1 : t2) + b * (C_DIM * S_DIM);
      ushort* dst = (tt ? t1bfT : t2bfT) + b * (S_DIM * C_DIM);
      float a = 0.f;
      #pragma unroll
      for (int k = 0; k < 16; ++k) {
        int c = cg + 16 * k;
        float v = src[c * S_DIM + s0 + ls];
        a += v * v;
        tl[ls][c] = f2bf(v);
      }
      ps[cg][ls] = a;
      __syncthreads();
      if (tid < 16) {
        float ss = 0.f;
        #pragma unroll
        for (int j = 0; j < 16; ++j) ss += ps[j][tid];
        (tt ? ss1 : ss2)[b * S_DIM + s0 + tid] = ss;
      }
      #pragma unroll
      for (int i = 0; i < 4; ++i) {
        int sl = wv * 4 + i;
        u16x4 pk = *reinterpret_cast<const u16x4*>(&tl[sl][ln * 4]);
        *reinterpret_cast<u16x4*>(&dst[(s0 + sl) * C_DIM + ln * 4]) = pk;
      }
      __syncthreads();
    }
  } else {
    __shared__ int c_lds[S_DIM];
    int p = blk - 64;
    if (blk == 64 && tid == 0) *ticket = 0;   // re-arm last-arriver each call
    c_lds[tid] = 0; c_lds[tid + 256] = 0;
    __syncthreads();
    atomicAdd(&c_lds[idx[p * K_DIM + tid]], 1);
    atomicAdd(&c_lds[idx[p * K_DIM + tid + 256]], 1);
    __syncthreads();
    cntbf[p * S_DIM + tid]       = f2bf((float)c_lds[tid]);
    cntbf[p * S_DIM + tid + 256] = f2bf((float)c_lds[tid + 256]);
  }
}

// K2: MFMA Gram + exp. Per wave: one 16x16 (s,t) tile, K=256 via 8 MFMA,
// fragments direct from L2 (rows of t2bfT/t1bfT). Epilogue: scales+exp,
// write bf16 E (4 b16 stores) + ET (packed ushort4) + fp32 diag.
__global__ __launch_bounds__(256) void gemm_exp_mfma_kernel(
    const ushort* __restrict__ t2bfT, const ushort* __restrict__ t1bfT,
    const float* __restrict__ ss2, const float* __restrict__ ss1,
    ushort* __restrict__ Ebf, ushort* __restrict__ ETbf,
    float* __restrict__ diag) {
  int wave = threadIdx.x >> 6, lane = threadIdx.x & 63;
  int job = blockIdx.x * 4 + wave;          // 0..2047
  int n = job & 31, m = (job >> 5) & 31, b = job >> 10;
  int m0 = m * 16, c0 = n * 16;
  int lr = lane & 15, lo = lane >> 4;
  const ushort* ap = t2bfT + b * (S_DIM * C_DIM) + (m0 + lr) * C_DIM + lo * 8;
  const ushort* bp = t1bfT + b * (S_DIM * C_DIM) + (c0 + lr) * C_DIM + lo * 8;
  f32x4 acc = {0.f, 0.f, 0.f, 0.f};
  #pragma unroll
  for (int k = 0; k < 8; ++k) {
    bf16x8 af = *reinterpret_cast<const bf16x8*>(ap + k * 32);
    bf16x8 bv = *reinterpret_cast<const bf16x8*>(bp + k * 32);
    acc = __builtin_amdgcn_mfma_f32_16x16x32_bf16(af, bv, acc, 0, 0, 0);
  }
  float bs = 1.0f / fmaxf(sqrtf(ss1[b * S_DIM + c0 + lr]), 1e-12f);
  float e[4]; ushort eb[4];
  ushort* Eb  = Ebf  + b * (S_DIM * S_DIM);
  ushort* ETb = ETbf + b * (S_DIM * S_DIM);
  #pragma unroll
  for (int r = 0; r < 4; ++r) {
    int row = m0 + lo * 4 + r;
    float as = 1.0f / fmaxf(sqrtf(ss2[b * S_DIM + row]), 1e-12f);
    e[r] = expf(acc[r] * as * bs * INV_BW);
    eb[r] = f2bf(e[r]);
    Eb[row * S_DIM + c0 + lr] = eb[r];
  }
  u16x4 pk = {eb[0], eb[1], eb[2], eb[3]};
  *reinterpret_cast<u16x4*>(&ETb[(c0 + lr) * S_DIM + m0 + lo * 4]) = pk;
  if (m == n && (lr >> 2) == lo) diag[b * S_DIM + m0 + lr] = e[lr & 3];
}

// K3: MFMA denominators. D1[p,b,t] = sum_s cnt[p,s]E[b,s,t] (B from ETbf),
//     D2[p,b,s] = sum_t cnt[p,t]E[b,s,t] (B from Ebf). K split in 2 halves.
__global__ __launch_bounds__(256) void denom_mfma_kernel(
    const ushort* __restrict__ Ebf, const ushort* __restrict__ ETbf,
    const ushort* __restrict__ cntbf,
    float* __restrict__ D1p, float* __restrict__ D2p) {
  int wave = threadIdx.x >> 6, lane = threadIdx.x & 63;
  int job = blockIdx.x * 4 + wave;          // 0..2047
  int n = job & 31, m = (job >> 5) & 7, b = (job >> 8) & 1;
  int z = (job >> 9) & 1, h = job >> 10;
  int m0 = m * 16, col0 = n * 16;
  const ushort* Bmat = (z ? Ebf : ETbf) + b * (S_DIM * S_DIM);
  float* Dp = (z ? D2p : D1p) + h * (P_DIM * 2 * S_DIM);
  int lr = lane & 15, lo = lane >> 4;
  const ushort* aptr = cntbf + (m0 + lr) * S_DIM + h * 256 + lo * 8;
  const ushort* bptr = Bmat + (col0 + lr) * S_DIM + h * 256 + lo * 8;
  f32x4 acc = {0.f, 0.f, 0.f, 0.f};
  #pragma unroll
  for (int k = 0; k < 8; ++k) {
    bf16x8 af = *reinterpret_cast<const bf16x8*>(aptr + k * 32);
    bf16x8 bv = *reinterpret_cast<const bf16x8*>(bptr + k * 32);
    acc = __builtin_amdgcn_mfma_f32_16x16x32_bf16(af, bv, acc, 0, 0, 0);
  }
  #pragma unroll
  for (int r = 0; r < 4; ++r) {
    int p = m0 + lo * 4 + r;
    Dp[(p * 2 + b) * S_DIM + col0 + lr] = acc[r];
  }
}

// K4: loss terms + last-arriver final reduction.
__global__ __launch_bounds__(512) void loss_final_kernel(
    const int* __restrict__ idx, const float* __restrict__ diag,
    const float* __restrict__ D1p, const float* __restrict__ D2p,
    float* __restrict__ part, int* __restrict__ ticket, float* __restrict__ out) {
  const int HOFF = P_DIM * 2 * S_DIM;
  int p = blockIdx.x, k = threadIdx.x;
  int s = idx[p * K_DIM + k];
  float acc = 0.f;
  #pragma unroll
  for (int b = 0; b < 2; ++b) {
    float pos = diag[b * S_DIM + s];
    int o = (p * 2 + b) * S_DIM + s;
    float d1 = D1p[o] + D1p[HOFF + o];
    float d2 = D2p[o] + D2p[HOFF + o];
    acc += logf(0.5f * (pos / d1 + pos / d2) + EPS_LOSS);
  }
  for (int o = 32; o; o >>= 1) acc += __shfl_down(acc, o);
  __shared__ float red[8];
  __shared__ int lastflag;
  if ((k & 63) == 0) red[k >> 6] = acc;
  __syncthreads();
  if (k == 0) {
    float tsum = 0.f;
    #pragma unroll
    for (int i = 0; i < 8; ++i) tsum += red[i];
    atomicExch(&part[p], tsum);
    __threadfence();
    int old = atomicAdd(ticket, 1);
    lastflag = (old == P_DIM - 1);
  }
  __syncthreads();
  if (lastflag) {
    __threadfence();
    float v = (k < P_DIM) ? atomicAdd(&part[k], 0.0f) : 0.0f;
    for (int o = 32; o; o >>= 1) v += __shfl_down(v, o);
    __shared__ float red2[8];
    if ((k & 63) == 0) red2[k >> 6] = v;
    __syncthreads();
    if (k == 0) {
      float tsum = 0.f;
      #pragma unroll
      for (int i = 0; i < 8; ++i) tsum += red2[i];
      out[0] = -tsum * (1.0f / (P_DIM * 2.0f * K_DIM));
    }
  }
}

extern "C" void kernel_launch(void* const* d_in, const int* in_sizes, int n_in,
                              void* d_out, int out_size, void* d_ws, size_t ws_size,
                              hipStream_t stream) {
  const float* t2 = (const float*)d_in[0];
  const float* t1 = (const float*)d_in[1];
  const int* idx  = (const int*)d_in[2];
  float* ws = (float*)d_ws;
  float*  ss2    = ws + OFF_SS2;
  float*  ss1    = ws + OFF_SS1;
  float*  diag   = ws + OFF_DIAG;
  ushort* cntbf  = (ushort*)(ws + OFF_CNTBF);
  ushort* t2bfT  = (ushort*)(ws + OFF_T2BF);
  ushort* t1bfT  = (ushort*)(ws + OFF_T1BF);
  ushort* Ebf    = (ushort*)(ws + OFF_EBF);
  ushort* ETbf   = (ushort*)(ws + OFF_ETBF);
  float*  D1p    = ws + OFF_D1P;      // aliases t2bfT/t1bfT (dead by then)
  float*  D2p    = ws + OFF_D2P;
  float*  part   = ws + OFF_PART;
  int*    ticket = (int*)(ws + OFF_TICKET);

  pre_kernel<<<192, 256, 0, stream>>>(t2, t1, idx, ss2, ss1, t2bfT, t1bfT,
                                      cntbf, ticket);
  gemm_exp_mfma_kernel<<<512, 256, 0, stream>>>(t2bfT, t1bfT, ss2, ss1,
                                                Ebf, ETbf, diag);
  denom_mfma_kernel<<<512, 256, 0, stream>>>(Ebf, ETbf, cntbf, D1p, D2p);
  loss_final_kernel<<<P_DIM, 512, 0, stream>>>(idx, diag, D1p, D2p, part, ticket,
                                               (float*)d_out);
}